// Round 1
// baseline (511.375 us; speedup 1.0000x reference)
//
#include <hip/hip_runtime.h>
#include <hip/hip_bf16.h>
#include <cstdint>

#define HID 128
#define NH 8
#define HD 16
#define QKV_NWCHUNK 512

// ---------------- CSR build ----------------

__global__ __launch_bounds__(256) void count_kernel(const int* __restrict__ dst,
                                                    int* __restrict__ counts, int E) {
  int e = blockIdx.x * 256 + threadIdx.x;
  if (e < E) atomicAdd(&counts[dst[e]], 1);
}

__global__ __launch_bounds__(1024) void scan_kernel(const int* __restrict__ counts,
                                                    int* __restrict__ offsets,
                                                    int* __restrict__ cursors, int n) {
  __shared__ int wsum[16];
  __shared__ int carry_s;
  const int tid = threadIdx.x;
  const int lane = tid & 63;
  const int wid = tid >> 6;
  if (tid == 0) carry_s = 0;
  __syncthreads();
  for (int base = 0; base < n; base += 1024) {
    int i = base + tid;
    int x0 = (i < n) ? counts[i] : 0;
    int x = x0;
#pragma unroll
    for (int off = 1; off < 64; off <<= 1) {
      int t = __shfl_up(x, off);
      if (lane >= off) x += t;
    }
    if (lane == 63) wsum[wid] = x;
    __syncthreads();
    if (wid == 0) {
      int w = (lane < 16) ? wsum[lane] : 0;
#pragma unroll
      for (int off = 1; off < 16; off <<= 1) {
        int t = __shfl_up(w, off);
        if (lane >= off) w += t;
      }
      if (lane < 16) wsum[lane] = w;
    }
    __syncthreads();
    int carry = carry_s;
    int waveoff = (wid > 0) ? wsum[wid - 1] : 0;
    int excl = carry + waveoff + (x - x0);   // exclusive prefix + global carry
    if (i < n) { offsets[i] = excl; cursors[i] = excl; }
    int total = wsum[15];
    __syncthreads();
    if (tid == 0) carry_s = carry + total;
    __syncthreads();
  }
  if (tid == 0) offsets[n] = carry_s;
}

__global__ __launch_bounds__(256) void scatter_kernel(const int* __restrict__ src,
                                                      const int* __restrict__ dst,
                                                      int* __restrict__ cursors,
                                                      int* __restrict__ csr_src, int E) {
  int e = blockIdx.x * 256 + threadIdx.x;
  if (e < E) {
    int pos = atomicAdd(&cursors[dst[e]], 1);
    csr_src[pos] = src[e];
  }
}

// ---------------- QKV projection ----------------
// out = h @ W.T + b.  Wave-level weight-stationary GEMM:
// 12 col-groups (3 matrices x 4 groups of 32 cols). Lane l: kc = l&7 (16-float
// k-chunk), og = l>>3. Lane holds W[o0+8m+og][kc*16..+15] for m=0..3 in regs.
__device__ __forceinline__ float dot16(const float4 w[4], float4 a, float4 b, float4 c, float4 d) {
  return w[0].x*a.x + w[0].y*a.y + w[0].z*a.z + w[0].w*a.w
       + w[1].x*b.x + w[1].y*b.y + w[1].z*b.z + w[1].w*b.w
       + w[2].x*c.x + w[2].y*c.y + w[2].z*c.z + w[2].w*c.w
       + w[3].x*d.x + w[3].y*d.y + w[3].z*d.z + w[3].w*d.w;
}

__global__ __launch_bounds__(256) void qkv_kernel(
    const float* __restrict__ h,
    const float* __restrict__ W0, const float* __restrict__ b0,
    const float* __restrict__ W1, const float* __restrict__ b1,
    const float* __restrict__ W2, const float* __restrict__ b2,
    float* __restrict__ Q, float* __restrict__ K, float* __restrict__ V,
    int n) {
  const int tid = threadIdx.x;
  const int lane = tid & 63;
  const int gw = blockIdx.x * 4 + (tid >> 6);
  const int colgrp = gw % 12;
  const int nw = gw / 12;
  const int mat = colgrp >> 2;
  const int o0 = (colgrp & 3) * 32;
  const float* Wm = (mat == 0) ? W0 : (mat == 1) ? W1 : W2;
  const float* bm = (mat == 0) ? b0 : (mat == 1) ? b1 : b2;
  float* Om = (mat == 0) ? Q : (mat == 1) ? K : V;
  const int kc = lane & 7;
  const int og = lane >> 3;

  float4 wr[4][4];
  float bias[4];
#pragma unroll
  for (int m = 0; m < 4; ++m) {
    int o = o0 + 8 * m + og;
    const float4* wp = (const float4*)(Wm + o * HID + kc * 16);
#pragma unroll
    for (int j = 0; j < 4; ++j) wr[m][j] = wp[j];
    bias[m] = bm[o];
  }

  const int CH = (n + QKV_NWCHUNK - 1) / QKV_NWCHUNK;
  int n0 = nw * CH;
  int n1 = min(n, n0 + CH);
  for (int nn = n0; nn < n1; ++nn) {
    const float4* hp = (const float4*)(h + (size_t)nn * HID + kc * 16);
    float4 h0 = hp[0], h1 = hp[1], h2 = hp[2], h3 = hp[3];
    float p[4];
#pragma unroll
    for (int m = 0; m < 4; ++m) p[m] = dot16(wr[m], h0, h1, h2, h3);
#pragma unroll
    for (int m = 0; m < 4; ++m) {
      p[m] += __shfl_xor(p[m], 1);
      p[m] += __shfl_xor(p[m], 2);
      p[m] += __shfl_xor(p[m], 4);
    }
    if (kc == 0) {
#pragma unroll
      for (int m = 0; m < 4; ++m)
        Om[(size_t)nn * HID + o0 + 8 * m + og] = p[m] + bias[m];
    }
  }
}

// ---------------- fused segment softmax + V aggregation ----------------
// One wave per node. lane -> (head = lane>>3, dim-pair = lane&7). Online softmax.
__global__ __launch_bounds__(256) void agg_kernel(
    const float* __restrict__ Q, const float* __restrict__ K, const float* __restrict__ V,
    const int* __restrict__ offsets, const int* __restrict__ csr_src,
    float* __restrict__ out, int n) {
  const int tid = threadIdx.x;
  const int lane = tid & 63;
  const int node = blockIdx.x * 4 + (tid >> 6);
  if (node >= n) return;
  const float2 q = ((const float2*)Q)[(size_t)node * 64 + lane];
  const int beg = offsets[node];
  const int end = offsets[node + 1];
  float m = -INFINITY, sum = 0.f, ax = 0.f, ay = 0.f;
  for (int i = beg; i < end; ++i) {
    int s = csr_src[i];
    float2 k = ((const float2*)K)[(size_t)s * 64 + lane];
    float p = q.x * k.x + q.y * k.y;
    p += __shfl_xor(p, 1);
    p += __shfl_xor(p, 2);
    p += __shfl_xor(p, 4);
    float score = p * 0.25f;                 // 1/sqrt(16)
    float mnew = fmaxf(m, score);
    float scale = __expf(m - mnew);          // first iter: exp(-inf)=0
    float w = __expf(score - mnew);
    float2 v = ((const float2*)V)[(size_t)s * 64 + lane];
    sum = sum * scale + w;
    ax = ax * scale + w * v.x;
    ay = ay * scale + w * v.y;
    m = mnew;
  }
  float inv = (sum > 0.f) ? 1.f / sum : 0.f;  // zero-degree nodes -> 0 (matches ref)
  ((float2*)out)[(size_t)node * 64 + lane] = make_float2(ax * inv, ay * inv);
}

// ---------------- launch ----------------

extern "C" void kernel_launch(void* const* d_in, const int* in_sizes, int n_in,
                              void* d_out, int out_size, void* d_ws, size_t ws_size,
                              hipStream_t stream) {
  const float* h  = (const float*)d_in[0];
  const int* src  = (const int*)d_in[1];
  const int* dst  = (const int*)d_in[2];
  const float* WQ = (const float*)d_in[3];
  const float* bQ = (const float*)d_in[4];
  const float* WK = (const float*)d_in[5];
  const float* bK = (const float*)d_in[6];
  const float* WV = (const float*)d_in[7];
  const float* bV = (const float*)d_in[8];
  float* out = (float*)d_out;

  const int n = in_sizes[0] / HID;
  const int E = in_sizes[1];

  float* Q = (float*)d_ws;
  float* K = Q + (size_t)n * HID;
  float* V = K + (size_t)n * HID;
  int* counts  = (int*)(V + (size_t)n * HID);
  int* offsets = counts + n;        // n+1 entries
  int* cursors = offsets + n + 1;
  int* csr_src = cursors + n;       // E entries

  hipMemsetAsync(counts, 0, (size_t)n * sizeof(int), stream);
  count_kernel<<<(E + 255) / 256, 256, 0, stream>>>(dst, counts, E);
  scan_kernel<<<1, 1024, 0, stream>>>(counts, offsets, cursors, n);
  scatter_kernel<<<(E + 255) / 256, 256, 0, stream>>>(src, dst, cursors, csr_src, E);
  qkv_kernel<<<12 * QKV_NWCHUNK / 4, 256, 0, stream>>>(h, WQ, bQ, WK, bK, WV, bV, Q, K, V, n);
  agg_kernel<<<(n + 3) / 4, 256, 0, stream>>>(Q, K, V, offsets, csr_src, out, n);
}

// Round 2
// 301.438 us; speedup vs baseline: 1.6964x; 1.6964x over previous
//
#include <hip/hip_runtime.h>
#include <hip/hip_bf16.h>
#include <cstdint>

#define HID 128
#define NH 8
#define HD 16

// ---------------- CSR build ----------------

__global__ __launch_bounds__(256) void count_kernel(const int* __restrict__ dst,
                                                    int* __restrict__ counts, int E) {
  int e = blockIdx.x * 256 + threadIdx.x;
  if (e < E) atomicAdd(&counts[dst[e]], 1);
}

__global__ __launch_bounds__(1024) void scan_kernel(const int* __restrict__ counts,
                                                    int* __restrict__ offsets,
                                                    int* __restrict__ cursors, int n) {
  __shared__ int wsum[16];
  __shared__ int carry_s;
  const int tid = threadIdx.x;
  const int lane = tid & 63;
  const int wid = tid >> 6;
  if (tid == 0) carry_s = 0;
  __syncthreads();
  for (int base = 0; base < n; base += 1024) {
    int i = base + tid;
    int x0 = (i < n) ? counts[i] : 0;
    int x = x0;
#pragma unroll
    for (int off = 1; off < 64; off <<= 1) {
      int t = __shfl_up(x, off);
      if (lane >= off) x += t;
    }
    if (lane == 63) wsum[wid] = x;
    __syncthreads();
    if (wid == 0) {
      int w = (lane < 16) ? wsum[lane] : 0;
#pragma unroll
      for (int off = 1; off < 16; off <<= 1) {
        int t = __shfl_up(w, off);
        if (lane >= off) w += t;
      }
      if (lane < 16) wsum[lane] = w;
    }
    __syncthreads();
    int carry = carry_s;
    int waveoff = (wid > 0) ? wsum[wid - 1] : 0;
    int excl = carry + waveoff + (x - x0);
    if (i < n) { offsets[i] = excl; cursors[i] = excl; }
    int total = wsum[15];
    __syncthreads();
    if (tid == 0) carry_s = carry + total;
    __syncthreads();
  }
  if (tid == 0) offsets[n] = carry_s;
}

__global__ __launch_bounds__(256) void scatter_kernel(const int* __restrict__ src,
                                                      const int* __restrict__ dst,
                                                      int* __restrict__ cursors,
                                                      int* __restrict__ csr_src, int E) {
  int e = blockIdx.x * 256 + threadIdx.x;
  if (e < E) {
    int pos = atomicAdd(&cursors[dst[e]], 1);
    csr_src[pos] = src[e];
  }
}

// ---------------- QKV projection: tiled f32 GEMM, bf16 output ----------------
// C[n x 384] = h[n x 128] @ Wcat^T, Wcat rows = [WQ;WK;WV][384][128].
// Block: BM=64 nodes x BN=64 cols, full K=128 in LDS (transposed). 256 thr.
__global__ __launch_bounds__(256) void qkv_gemm(
    const float* __restrict__ h,
    const float* __restrict__ W0, const float* __restrict__ b0,
    const float* __restrict__ W1, const float* __restrict__ b1,
    const float* __restrict__ W2, const float* __restrict__ b2,
    __hip_bfloat16* __restrict__ Q, __hip_bfloat16* __restrict__ K,
    __hip_bfloat16* __restrict__ V, int n) {
  __shared__ float As[128][64];  // [k][m]   32 KB
  __shared__ float Bs[128][64];  // [k][col] 32 KB
  const int tid = threadIdx.x;
  const int m0 = blockIdx.x * 64;
  const int bn = blockIdx.y;           // 0..5
  const int mat = bn >> 1;
  const int c0 = (bn & 1) * 64;        // within-matrix col offset
  const float* Wm = (mat == 0) ? W0 : (mat == 1) ? W1 : W2;
  const float* bm = (mat == 0) ? b0 : (mat == 1) ? b1 : b2;
  __hip_bfloat16* Om = (mat == 0) ? Q : (mat == 1) ? K : V;

  // stage: thread t -> row r = t>>2 (64 rows), k-chunk kc = t&3 (32 k each)
  {
    const int r = tid >> 2, kc = tid & 3;
    const int gm = m0 + r;
    const bool ok = gm < n;
    const float4* hp = (const float4*)(h + (size_t)gm * HID + kc * 32);
    const float4* wp = (const float4*)(Wm + (size_t)(c0 + r) * HID + kc * 32);
#pragma unroll
    for (int j = 0; j < 8; ++j) {
      float4 x = ok ? hp[j] : make_float4(0.f, 0.f, 0.f, 0.f);
      int k = kc * 32 + j * 4;
      As[k + 0][r] = x.x; As[k + 1][r] = x.y; As[k + 2][r] = x.z; As[k + 3][r] = x.w;
    }
#pragma unroll
    for (int j = 0; j < 8; ++j) {
      float4 x = wp[j];
      int k = kc * 32 + j * 4;
      Bs[k + 0][r] = x.x; Bs[k + 1][r] = x.y; Bs[k + 2][r] = x.z; Bs[k + 3][r] = x.w;
    }
  }
  __syncthreads();

  const int tm = (tid & 15) * 4;       // node sub-block
  const int tn = (tid >> 4) * 4;       // col sub-block
  float acc[4][4] = {};
#pragma unroll 4
  for (int k = 0; k < 128; ++k) {
    float4 a = *(const float4*)&As[k][tm];
    float4 b = *(const float4*)&Bs[k][tn];
    acc[0][0] += a.x * b.x; acc[0][1] += a.x * b.y; acc[0][2] += a.x * b.z; acc[0][3] += a.x * b.w;
    acc[1][0] += a.y * b.x; acc[1][1] += a.y * b.y; acc[1][2] += a.y * b.z; acc[1][3] += a.y * b.w;
    acc[2][0] += a.z * b.x; acc[2][1] += a.z * b.y; acc[2][2] += a.z * b.z; acc[2][3] += a.z * b.w;
    acc[3][0] += a.w * b.x; acc[3][1] += a.w * b.y; acc[3][2] += a.w * b.z; acc[3][3] += a.w * b.w;
  }

  const int colb = c0 + tn;
  float bias0 = bm[colb + 0], bias1 = bm[colb + 1], bias2 = bm[colb + 2], bias3 = bm[colb + 3];
#pragma unroll
  for (int i = 0; i < 4; ++i) {
    int gm = m0 + tm + i;
    if (gm < n) {
      ushort4 u;
      u.x = __bfloat16_as_ushort(__float2bfloat16(acc[i][0] + bias0));
      u.y = __bfloat16_as_ushort(__float2bfloat16(acc[i][1] + bias1));
      u.z = __bfloat16_as_ushort(__float2bfloat16(acc[i][2] + bias2));
      u.w = __bfloat16_as_ushort(__float2bfloat16(acc[i][3] + bias3));
      *(ushort4*)(Om + (size_t)gm * HID + colb) = u;
    }
  }
}

// ---------------- fused segment softmax + V aggregation ----------------
// One wave per node; lane -> (head = lane>>3, dim-pair = lane&7).
// bf16 K/V gathers (half traffic), 2-edge unroll for MLP + shorter dep chain.
__global__ __launch_bounds__(256) void agg_kernel(
    const uint32_t* __restrict__ Q, const uint32_t* __restrict__ K,
    const uint32_t* __restrict__ V,
    const int* __restrict__ offsets, const int* __restrict__ csr_src,
    float* __restrict__ out, int n) {
  const int tid = threadIdx.x;
  const int lane = tid & 63;
  const int node = blockIdx.x * 4 + (tid >> 6);
  if (node >= n) return;

  uint32_t qu = Q[(size_t)node * 64 + lane];
  const float qx = __uint_as_float(qu << 16);
  const float qy = __uint_as_float(qu & 0xffff0000u);

  const int beg = offsets[node];
  const int end = offsets[node + 1];
  float m = -INFINITY, sum = 0.f, ax = 0.f, ay = 0.f;
  int i = beg;
  for (; i + 1 < end; i += 2) {
    int s0 = csr_src[i], s1 = csr_src[i + 1];
    uint32_t k0 = K[(size_t)s0 * 64 + lane];
    uint32_t k1 = K[(size_t)s1 * 64 + lane];
    uint32_t v0 = V[(size_t)s0 * 64 + lane];
    uint32_t v1 = V[(size_t)s1 * 64 + lane];
    float p0 = qx * __uint_as_float(k0 << 16) + qy * __uint_as_float(k0 & 0xffff0000u);
    float p1 = qx * __uint_as_float(k1 << 16) + qy * __uint_as_float(k1 & 0xffff0000u);
    p0 += __shfl_xor(p0, 1); p1 += __shfl_xor(p1, 1);
    p0 += __shfl_xor(p0, 2); p1 += __shfl_xor(p1, 2);
    p0 += __shfl_xor(p0, 4); p1 += __shfl_xor(p1, 4);
    float sc0 = p0 * 0.25f, sc1 = p1 * 0.25f;
    float mnew = fmaxf(m, fmaxf(sc0, sc1));
    float scale = __expf(m - mnew);
    float w0 = __expf(sc0 - mnew);
    float w1 = __expf(sc1 - mnew);
    sum = sum * scale + w0 + w1;
    ax = ax * scale + w0 * __uint_as_float(v0 << 16) + w1 * __uint_as_float(v1 << 16);
    ay = ay * scale + w0 * __uint_as_float(v0 & 0xffff0000u) + w1 * __uint_as_float(v1 & 0xffff0000u);
    m = mnew;
  }
  if (i < end) {
    int s0 = csr_src[i];
    uint32_t k0 = K[(size_t)s0 * 64 + lane];
    uint32_t v0 = V[(size_t)s0 * 64 + lane];
    float p0 = qx * __uint_as_float(k0 << 16) + qy * __uint_as_float(k0 & 0xffff0000u);
    p0 += __shfl_xor(p0, 1);
    p0 += __shfl_xor(p0, 2);
    p0 += __shfl_xor(p0, 4);
    float sc0 = p0 * 0.25f;
    float mnew = fmaxf(m, sc0);
    float scale = __expf(m - mnew);
    float w0 = __expf(sc0 - mnew);
    sum = sum * scale + w0;
    ax = ax * scale + w0 * __uint_as_float(v0 << 16);
    ay = ay * scale + w0 * __uint_as_float(v0 & 0xffff0000u);
  }
  float inv = (sum > 0.f) ? 1.f / sum : 0.f;  // zero-degree nodes -> 0 (matches ref)
  ((float2*)out)[(size_t)node * 64 + lane] = make_float2(ax * inv, ay * inv);
}

// ---------------- launch ----------------

extern "C" void kernel_launch(void* const* d_in, const int* in_sizes, int n_in,
                              void* d_out, int out_size, void* d_ws, size_t ws_size,
                              hipStream_t stream) {
  const float* h  = (const float*)d_in[0];
  const int* src  = (const int*)d_in[1];
  const int* dst  = (const int*)d_in[2];
  const float* WQ = (const float*)d_in[3];
  const float* bQ = (const float*)d_in[4];
  const float* WK = (const float*)d_in[5];
  const float* bK = (const float*)d_in[6];
  const float* WV = (const float*)d_in[7];
  const float* bV = (const float*)d_in[8];
  float* out = (float*)d_out;

  const int n = in_sizes[0] / HID;
  const int E = in_sizes[1];

  __hip_bfloat16* Q = (__hip_bfloat16*)d_ws;
  __hip_bfloat16* K = Q + (size_t)n * HID;
  __hip_bfloat16* V = K + (size_t)n * HID;
  int* counts  = (int*)(V + (size_t)n * HID);
  int* offsets = counts + n;        // n+1 entries
  int* cursors = offsets + n + 1;
  int* csr_src = cursors + n;       // E entries

  hipMemsetAsync(counts, 0, (size_t)n * sizeof(int), stream);
  count_kernel<<<(E + 255) / 256, 256, 0, stream>>>(dst, counts, E);
  scan_kernel<<<1, 1024, 0, stream>>>(counts, offsets, cursors, n);
  scatter_kernel<<<(E + 255) / 256, 256, 0, stream>>>(src, dst, cursors, csr_src, E);
  dim3 ggrid((n + 63) / 64, 6);
  qkv_gemm<<<ggrid, 256, 0, stream>>>(h, WQ, bQ, WK, bK, WV, bV, Q, K, V, n);
  agg_kernel<<<(n + 3) / 4, 256, 0, stream>>>((const uint32_t*)Q, (const uint32_t*)K,
                                              (const uint32_t*)V, offsets, csr_src, out, n);
}

// Round 3
// 220.435 us; speedup vs baseline: 2.3198x; 1.3675x over previous
//
#include <hip/hip_runtime.h>
#include <hip/hip_bf16.h>
#include <cstdint>

#define HID 128
#define NH 8
#define HD 16

typedef __attribute__((ext_vector_type(8))) short bf16x8;
typedef __attribute__((ext_vector_type(4))) float f32x4;

__device__ __forceinline__ short bfr(float x) {
  return (short)__bfloat16_as_ushort(__float2bfloat16(x));
}

// ---------------- CSR build ----------------

__global__ __launch_bounds__(256) void count_kernel(const int* __restrict__ dst,
                                                    int* __restrict__ counts, int E) {
  int e = blockIdx.x * 256 + threadIdx.x;
  if (e < E) atomicAdd(&counts[dst[e]], 1);
}

// hierarchical scan: per-block local exclusive scan + block totals
__global__ __launch_bounds__(256) void scan1_kernel(const int* __restrict__ counts,
                                                    int* __restrict__ offsets,
                                                    int* __restrict__ bsum, int n) {
  __shared__ int ws[4];
  const int t = threadIdx.x, b = blockIdx.x;
  const int i = b * 256 + t;
  const int lane = t & 63, wid = t >> 6;
  int x0 = (i < n) ? counts[i] : 0;
  int x = x0;
#pragma unroll
  for (int off = 1; off < 64; off <<= 1) {
    int v = __shfl_up(x, off);
    if (lane >= off) x += v;
  }
  if (lane == 63) ws[wid] = x;
  __syncthreads();
  int wpre = 0;
#pragma unroll
  for (int j = 0; j < 4; ++j) if (j < wid) wpre += ws[j];
  if (i < n) offsets[i] = wpre + x - x0;
  if (t == 0) bsum[b] = ws[0] + ws[1] + ws[2] + ws[3];
}

__global__ __launch_bounds__(256) void scan2_kernel(int* __restrict__ bsum,
                                                    int* __restrict__ offsets,
                                                    int nb, int n) {
  __shared__ int ws[4];
  const int t = threadIdx.x;
  const int lane = t & 63, wid = t >> 6;
  int x0 = (t < nb) ? bsum[t] : 0;
  int x = x0;
#pragma unroll
  for (int off = 1; off < 64; off <<= 1) {
    int v = __shfl_up(x, off);
    if (lane >= off) x += v;
  }
  if (lane == 63) ws[wid] = x;
  __syncthreads();
  int wpre = 0;
#pragma unroll
  for (int j = 0; j < 4; ++j) if (j < wid) wpre += ws[j];
  if (t < nb) bsum[t] = wpre + x - x0;
  if (t == 255) offsets[n] = wpre + x;  // grand total = E
}

__global__ __launch_bounds__(256) void scan3_kernel(int* __restrict__ offsets,
                                                    int* __restrict__ cursors,
                                                    const int* __restrict__ bsum, int n) {
  const int i = blockIdx.x * 256 + threadIdx.x;
  if (i < n) {
    int v = offsets[i] + bsum[blockIdx.x];
    offsets[i] = v;
    cursors[i] = v;
  }
}

__global__ __launch_bounds__(256) void scatter_kernel(const int* __restrict__ src,
                                                      const int* __restrict__ dst,
                                                      int* __restrict__ cursors,
                                                      int* __restrict__ csr_src, int E) {
  int e = blockIdx.x * 256 + threadIdx.x;
  if (e < E) {
    int pos = atomicAdd(&cursors[dst[e]], 1);
    csr_src[pos] = src[e];
  }
}

// ---------------- weight convert f32 -> bf16, concat [384][128] ----------------
__global__ __launch_bounds__(256) void convw_kernel(const float* __restrict__ W0,
                                                    const float* __restrict__ W1,
                                                    const float* __restrict__ W2,
                                                    short* __restrict__ Wb) {
  int i = blockIdx.x * 256 + threadIdx.x;
  if (i < 3 * HID * HID) {
    int mat = i >> 14;          // /16384
    int j = i & 16383;
    const float* W = (mat == 0) ? W0 : (mat == 1) ? W1 : W2;
    Wb[i] = bfr(W[j]);
  }
}

// ---------------- QKV projection: MFMA bf16 GEMM ----------------
// C[n x 384] = h * Wcat^T. Block: BM=64 rows x BN=128 cols (one matrix),
// 4 waves; wave w covers cols w*32..w*32+31 (2 col-tiles of 16).
// LDS A layout: chunk-transposed [c][row][8 bf16], c = k/8 (16 chunks).
// Fragment ds_read: lane l -> row=l&15(+rt*16), kg=l>>4, chunk c=ks*4+kg.
__global__ __launch_bounds__(256) void qkv_mfma(
    const float* __restrict__ h, const short* __restrict__ Wb,
    const float* __restrict__ b0, const float* __restrict__ b1,
    const float* __restrict__ b2,
    ushort* __restrict__ Q, ushort* __restrict__ K, ushort* __restrict__ V,
    int n) {
  __shared__ short As[16 * 64 * 8];  // 16 KB
  const int tid = threadIdx.x;
  const int m0 = blockIdx.x * 64;
  const int mat = blockIdx.y;
  const float* bm = (mat == 0) ? b0 : (mat == 1) ? b1 : b2;
  ushort* Om = (mat == 0) ? Q : (mat == 1) ? K : V;

  // ---- stage h tile (f32 -> bf16, chunk-transposed) ----
  {
    const int row = tid >> 2, q = tid & 3;
    const int gm = m0 + row;
    const bool ok = gm < n;
    const float4* hp = (const float4*)(h + (size_t)gm * HID + q * 32);
#pragma unroll
    for (int j2 = 0; j2 < 4; ++j2) {
      float4 a = ok ? hp[2 * j2] : make_float4(0.f, 0.f, 0.f, 0.f);
      float4 b = ok ? hp[2 * j2 + 1] : make_float4(0.f, 0.f, 0.f, 0.f);
      bf16x8 c;
      c[0] = bfr(a.x); c[1] = bfr(a.y); c[2] = bfr(a.z); c[3] = bfr(a.w);
      c[4] = bfr(b.x); c[5] = bfr(b.y); c[6] = bfr(b.z); c[7] = bfr(b.w);
      int ch = q * 4 + j2;
      *(bf16x8*)&As[(ch * 64 + row) * 8] = c;
    }
  }
  __syncthreads();

  const int lane = tid & 63;
  const int w = tid >> 6;
  const int r16 = lane & 15;
  const int kg = lane >> 4;

  f32x4 acc[4][2] = {};
#pragma unroll
  for (int ks = 0; ks < 4; ++ks) {
    bf16x8 bfrag[2];
#pragma unroll
    for (int ct = 0; ct < 2; ++ct) {
      int gc = mat * HID + w * 32 + ct * 16 + r16;
      bfrag[ct] = *(const bf16x8*)(Wb + (size_t)gc * HID + ks * 32 + kg * 8);
    }
#pragma unroll
    for (int rt = 0; rt < 4; ++rt) {
      bf16x8 afrag = *(const bf16x8*)&As[((ks * 4 + kg) * 64 + rt * 16 + r16) * 8];
#pragma unroll
      for (int ct = 0; ct < 2; ++ct)
        acc[rt][ct] = __builtin_amdgcn_mfma_f32_16x16x32_bf16(afrag, bfrag[ct], acc[rt][ct], 0, 0, 0);
    }
  }

  // ---- epilogue: bias + bf16 store ----
#pragma unroll
  for (int ct = 0; ct < 2; ++ct) {
    const int colw = w * 32 + ct * 16 + r16;
    const float bias = bm[colw];
#pragma unroll
    for (int rt = 0; rt < 4; ++rt) {
#pragma unroll
      for (int r = 0; r < 4; ++r) {
        int gm = m0 + rt * 16 + kg * 4 + r;
        if (gm < n)
          Om[(size_t)gm * HID + colw] = __bfloat16_as_ushort(__float2bfloat16(acc[rt][ct][r] + bias));
      }
    }
  }
}

// ---------------- fused segment softmax + V aggregation ----------------
// One wave per node; lane -> (head = lane>>3, dim-pair = lane&7). Online
// softmax, 4-edge unroll (8 gathers in flight, one rescale per 4 edges).
__device__ __forceinline__ float red8(float p) {
  p += __shfl_xor(p, 1);
  p += __shfl_xor(p, 2);
  p += __shfl_xor(p, 4);
  return p;
}

__global__ __launch_bounds__(256) void agg_kernel(
    const uint32_t* __restrict__ Q, const uint32_t* __restrict__ K,
    const uint32_t* __restrict__ V,
    const int* __restrict__ offsets, const int* __restrict__ csr_src,
    float* __restrict__ out, int n) {
  const int tid = threadIdx.x;
  const int lane = tid & 63;
  const int node = blockIdx.x * 4 + (tid >> 6);
  if (node >= n) return;

  uint32_t qu = Q[(size_t)node * 64 + lane];
  const float qx = __uint_as_float(qu << 16);
  const float qy = __uint_as_float(qu & 0xffff0000u);

  const int beg = offsets[node];
  const int end = offsets[node + 1];
  float m = -INFINITY, sum = 0.f, ax = 0.f, ay = 0.f;
  int i = beg;
  for (; i + 3 < end; i += 4) {
    int s0 = csr_src[i], s1 = csr_src[i + 1], s2 = csr_src[i + 2], s3 = csr_src[i + 3];
    uint32_t k0 = K[(size_t)s0 * 64 + lane];
    uint32_t k1 = K[(size_t)s1 * 64 + lane];
    uint32_t k2 = K[(size_t)s2 * 64 + lane];
    uint32_t k3 = K[(size_t)s3 * 64 + lane];
    uint32_t v0 = V[(size_t)s0 * 64 + lane];
    uint32_t v1 = V[(size_t)s1 * 64 + lane];
    uint32_t v2 = V[(size_t)s2 * 64 + lane];
    uint32_t v3 = V[(size_t)s3 * 64 + lane];
    float p0 = qx * __uint_as_float(k0 << 16) + qy * __uint_as_float(k0 & 0xffff0000u);
    float p1 = qx * __uint_as_float(k1 << 16) + qy * __uint_as_float(k1 & 0xffff0000u);
    float p2 = qx * __uint_as_float(k2 << 16) + qy * __uint_as_float(k2 & 0xffff0000u);
    float p3 = qx * __uint_as_float(k3 << 16) + qy * __uint_as_float(k3 & 0xffff0000u);
    float sc0 = red8(p0) * 0.25f;
    float sc1 = red8(p1) * 0.25f;
    float sc2 = red8(p2) * 0.25f;
    float sc3 = red8(p3) * 0.25f;
    float mnew = fmaxf(fmaxf(fmaxf(sc0, sc1), fmaxf(sc2, sc3)), m);
    float scale = __expf(m - mnew);
    float w0 = __expf(sc0 - mnew), w1 = __expf(sc1 - mnew);
    float w2 = __expf(sc2 - mnew), w3 = __expf(sc3 - mnew);
    sum = sum * scale + w0 + w1 + w2 + w3;
    ax = ax * scale + w0 * __uint_as_float(v0 << 16) + w1 * __uint_as_float(v1 << 16)
                    + w2 * __uint_as_float(v2 << 16) + w3 * __uint_as_float(v3 << 16);
    ay = ay * scale + w0 * __uint_as_float(v0 & 0xffff0000u) + w1 * __uint_as_float(v1 & 0xffff0000u)
                    + w2 * __uint_as_float(v2 & 0xffff0000u) + w3 * __uint_as_float(v3 & 0xffff0000u);
    m = mnew;
  }
  for (; i < end; ++i) {
    int s0 = csr_src[i];
    uint32_t k0 = K[(size_t)s0 * 64 + lane];
    uint32_t v0 = V[(size_t)s0 * 64 + lane];
    float p0 = qx * __uint_as_float(k0 << 16) + qy * __uint_as_float(k0 & 0xffff0000u);
    float sc0 = red8(p0) * 0.25f;
    float mnew = fmaxf(m, sc0);
    float scale = __expf(m - mnew);
    float w0 = __expf(sc0 - mnew);
    sum = sum * scale + w0;
    ax = ax * scale + w0 * __uint_as_float(v0 << 16);
    ay = ay * scale + w0 * __uint_as_float(v0 & 0xffff0000u);
    m = mnew;
  }
  float inv = (sum > 0.f) ? 1.f / sum : 0.f;  // zero-degree nodes -> 0
  ((float2*)out)[(size_t)node * 64 + lane] = make_float2(ax * inv, ay * inv);
}

// ---------------- launch ----------------

extern "C" void kernel_launch(void* const* d_in, const int* in_sizes, int n_in,
                              void* d_out, int out_size, void* d_ws, size_t ws_size,
                              hipStream_t stream) {
  const float* h  = (const float*)d_in[0];
  const int* src  = (const int*)d_in[1];
  const int* dst  = (const int*)d_in[2];
  const float* WQ = (const float*)d_in[3];
  const float* bQ = (const float*)d_in[4];
  const float* WK = (const float*)d_in[5];
  const float* bK = (const float*)d_in[6];
  const float* WV = (const float*)d_in[7];
  const float* bV = (const float*)d_in[8];
  float* out = (float*)d_out;

  const int n = in_sizes[0] / HID;
  const int E = in_sizes[1];
  const int nb = (n + 255) / 256;

  ushort* Q = (ushort*)d_ws;
  ushort* K = Q + (size_t)n * HID;
  ushort* V = K + (size_t)n * HID;
  short* Wb = (short*)(V + (size_t)n * HID);        // 384*128
  int* counts  = (int*)(Wb + 384 * HID);
  int* offsets = counts + n;        // n+1 entries
  int* cursors = offsets + n + 1;
  int* csr_src = cursors + n;       // E entries
  int* bsum    = csr_src + E;       // nb entries

  hipMemsetAsync(counts, 0, (size_t)n * sizeof(int), stream);
  count_kernel<<<(E + 255) / 256, 256, 0, stream>>>(dst, counts, E);
  scan1_kernel<<<nb, 256, 0, stream>>>(counts, offsets, bsum, n);
  scan2_kernel<<<1, 256, 0, stream>>>(bsum, offsets, nb, n);
  scan3_kernel<<<nb, 256, 0, stream>>>(offsets, cursors, bsum, n);
  scatter_kernel<<<(E + 255) / 256, 256, 0, stream>>>(src, dst, cursors, csr_src, E);
  convw_kernel<<<(3 * HID * HID + 255) / 256, 256, 0, stream>>>(WQ, WK, WV, Wb);
  dim3 ggrid((n + 63) / 64, 3);
  qkv_mfma<<<ggrid, 256, 0, stream>>>(h, Wb, bQ, bK, bV, Q, K, V, n);
  agg_kernel<<<(n + 3) / 4, 256, 0, stream>>>((const uint32_t*)Q, (const uint32_t*)K,
                                              (const uint32_t*)V, offsets, csr_src, out, n);
}

// Round 4
// 194.246 us; speedup vs baseline: 2.6326x; 1.1348x over previous
//
#include <hip/hip_runtime.h>
#include <hip/hip_bf16.h>
#include <cstdint>

#define HID 128
#define NH 8
#define HD 16

typedef __attribute__((ext_vector_type(8))) short bf16x8;
typedef __attribute__((ext_vector_type(4))) float f32x4;

#if __has_builtin(__builtin_amdgcn_exp2f)
#define EXP2(x) __builtin_amdgcn_exp2f(x)
#else
#define EXP2(x) exp2f(x)
#endif

__device__ __forceinline__ short bfr(float x) {
  return (short)__bfloat16_as_ushort(__float2bfloat16(x));
}

// ---------------- CSR build (+ fused weight convert) ----------------

__global__ __launch_bounds__(256) void count_conv_kernel(
    const int* __restrict__ dst, int* __restrict__ counts, int E,
    const float* __restrict__ W0, const float* __restrict__ W1,
    const float* __restrict__ W2, short* __restrict__ Wb) {
  int e = blockIdx.x * 256 + threadIdx.x;
  if (e < E) atomicAdd(&counts[dst[e]], 1);
  if (e < 3 * HID * HID) {
    int mat = e >> 14;
    int j = e & 16383;
    const float* W = (mat == 0) ? W0 : (mat == 1) ? W1 : W2;
    Wb[e] = bfr(W[j]);
  }
}

__global__ __launch_bounds__(256) void scan1_kernel(const int* __restrict__ counts,
                                                    int* __restrict__ offsets,
                                                    int* __restrict__ bsum, int n) {
  __shared__ int ws[4];
  const int t = threadIdx.x, b = blockIdx.x;
  const int i = b * 256 + t;
  const int lane = t & 63, wid = t >> 6;
  int x0 = (i < n) ? counts[i] : 0;
  int x = x0;
#pragma unroll
  for (int off = 1; off < 64; off <<= 1) {
    int v = __shfl_up(x, off);
    if (lane >= off) x += v;
  }
  if (lane == 63) ws[wid] = x;
  __syncthreads();
  int wpre = 0;
#pragma unroll
  for (int j = 0; j < 4; ++j) if (j < wid) wpre += ws[j];
  if (i < n) offsets[i] = wpre + x - x0;
  if (t == 0) bsum[b] = ws[0] + ws[1] + ws[2] + ws[3];
}

__global__ __launch_bounds__(256) void scan2_kernel(int* __restrict__ bsum,
                                                    int* __restrict__ offsets,
                                                    int nb, int n) {
  __shared__ int ws[4];
  const int t = threadIdx.x;
  const int lane = t & 63, wid = t >> 6;
  int x0 = (t < nb) ? bsum[t] : 0;
  int x = x0;
#pragma unroll
  for (int off = 1; off < 64; off <<= 1) {
    int v = __shfl_up(x, off);
    if (lane >= off) x += v;
  }
  if (lane == 63) ws[wid] = x;
  __syncthreads();
  int wpre = 0;
#pragma unroll
  for (int j = 0; j < 4; ++j) if (j < wid) wpre += ws[j];
  if (t < nb) bsum[t] = wpre + x - x0;
  if (t == 255) offsets[n] = wpre + x;  // grand total = E
}

__global__ __launch_bounds__(256) void scan3_kernel(int* __restrict__ offsets,
                                                    int* __restrict__ cursors,
                                                    const int* __restrict__ bsum, int n) {
  const int i = blockIdx.x * 256 + threadIdx.x;
  if (i < n) {
    int v = offsets[i] + bsum[blockIdx.x];
    offsets[i] = v;
    cursors[i] = v;
  }
}

__global__ __launch_bounds__(256) void scatter_kernel(const int* __restrict__ src,
                                                      const int* __restrict__ dst,
                                                      int* __restrict__ cursors,
                                                      int* __restrict__ csr_src, int E) {
  int e = blockIdx.x * 256 + threadIdx.x;
  if (e < E) {
    int pos = atomicAdd(&cursors[dst[e]], 1);
    csr_src[pos] = src[e];
  }
}

// ---------------- QKV projection: MFMA bf16 GEMM, all 3 mats per block ----------------
// Block: 64 node-rows, stage h once (bf16, chunk-transposed LDS), then per
// matrix: 128 cols via 4 waves (32 cols each), 96 MFMA/wave total.
// Operand-swapped: mfma(Wfrag, hfrag) -> lane holds 4 CONSECUTIVE cols of one
// node row -> packed 8B stores.
__global__ __launch_bounds__(256) void qkv_mfma(
    const float* __restrict__ h, const short* __restrict__ Wb,
    const float* __restrict__ b0, const float* __restrict__ b1,
    const float* __restrict__ b2,
    ushort* __restrict__ Q, ushort* __restrict__ K, ushort* __restrict__ V,
    int n) {
  __shared__ short As[16 * 64 * 8];  // 16 KB, [chunk c=k/8][row][8]
  const int tid = threadIdx.x;
  const int m0 = blockIdx.x * 64;

  // ---- stage h tile (f32 -> bf16, chunk-transposed) ----
  {
    const int row = tid >> 2, q = tid & 3;
    const int gm = m0 + row;
    const bool ok = gm < n;
    const float4* hp = (const float4*)(h + (size_t)gm * HID + q * 32);
#pragma unroll
    for (int j2 = 0; j2 < 4; ++j2) {
      float4 a = ok ? hp[2 * j2] : make_float4(0.f, 0.f, 0.f, 0.f);
      float4 b = ok ? hp[2 * j2 + 1] : make_float4(0.f, 0.f, 0.f, 0.f);
      bf16x8 c;
      c[0] = bfr(a.x); c[1] = bfr(a.y); c[2] = bfr(a.z); c[3] = bfr(a.w);
      c[4] = bfr(b.x); c[5] = bfr(b.y); c[6] = bfr(b.z); c[7] = bfr(b.w);
      int ch = q * 4 + j2;
      *(bf16x8*)&As[(ch * 64 + row) * 8] = c;
    }
  }
  __syncthreads();

  const int lane = tid & 63;
  const int w = tid >> 6;
  const int r16 = lane & 15;
  const int kg = lane >> 4;

  const float* bms[3] = {b0, b1, b2};
  ushort* Oms[3] = {Q, K, V};

#pragma unroll
  for (int mat = 0; mat < 3; ++mat) {
    f32x4 acc[2][4] = {};
#pragma unroll
    for (int ks = 0; ks < 4; ++ks) {
      bf16x8 wfrag[2];
#pragma unroll
      for (int ct = 0; ct < 2; ++ct) {
        int gc = mat * HID + w * 32 + ct * 16 + r16;
        wfrag[ct] = *(const bf16x8*)(Wb + (size_t)gc * HID + ks * 32 + kg * 8);
      }
#pragma unroll
      for (int rt = 0; rt < 4; ++rt) {
        bf16x8 hfrag = *(const bf16x8*)&As[((ks * 4 + kg) * 64 + rt * 16 + r16) * 8];
#pragma unroll
        for (int ct = 0; ct < 2; ++ct)
          acc[ct][rt] = __builtin_amdgcn_mfma_f32_16x16x32_bf16(wfrag[ct], hfrag, acc[ct][rt], 0, 0, 0);
      }
    }
    // epilogue: lane (r16,kg) holds cols col0..col0+3 of node row rt*16+r16
    const float* bm = bms[mat];
    ushort* Om = Oms[mat];
#pragma unroll
    for (int ct = 0; ct < 2; ++ct) {
      const int col0 = w * 32 + ct * 16 + kg * 4;
      const float4 bias = *(const float4*)(bm + col0);
#pragma unroll
      for (int rt = 0; rt < 4; ++rt) {
        int gm = m0 + rt * 16 + r16;
        if (gm < n) {
          float c0 = acc[ct][rt][0] + bias.x;
          float c1 = acc[ct][rt][1] + bias.y;
          float c2 = acc[ct][rt][2] + bias.z;
          float c3 = acc[ct][rt][3] + bias.w;
          uint2 u;
          u.x = (uint32_t)__bfloat16_as_ushort(__float2bfloat16(c0)) |
                ((uint32_t)__bfloat16_as_ushort(__float2bfloat16(c1)) << 16);
          u.y = (uint32_t)__bfloat16_as_ushort(__float2bfloat16(c2)) |
                ((uint32_t)__bfloat16_as_ushort(__float2bfloat16(c3)) << 16);
          *(uint2*)(Om + (size_t)gm * HID + col0) = u;
        }
      }
    }
  }
}

// ---------------- fused segment softmax + V aggregation ----------------
// One wave per node; lane -> (head = lane>>3, dim-pair = lane&7).
// 8-edge masked unroll, log2-domain online softmax.
__device__ __forceinline__ float red8(float p) {
  p += __shfl_xor(p, 1);
  p += __shfl_xor(p, 2);
  p += __shfl_xor(p, 4);
  return p;
}

__global__ __launch_bounds__(256) void agg_kernel(
    const uint32_t* __restrict__ Q, const uint32_t* __restrict__ K,
    const uint32_t* __restrict__ V,
    const int* __restrict__ offsets, const int* __restrict__ csr_src,
    float* __restrict__ out, int n) {
  const int tid = threadIdx.x;
  const int lane = tid & 63;
  const int node = blockIdx.x * 4 + (tid >> 6);
  if (node >= n) return;

  const float S = 0.25f * 1.44269504f;  // 1/sqrt(16) * log2(e)
  uint32_t qu = Q[(size_t)node * 64 + lane];
  const float qx = __uint_as_float(qu << 16) * S;
  const float qy = __uint_as_float(qu & 0xffff0000u) * S;

  const int beg = offsets[node];
  const int end = offsets[node + 1];
  float m2 = -INFINITY, sum = 0.f, ax = 0.f, ay = 0.f;

  for (int g = beg; g < end; g += 8) {
    int idx[8];
#pragma unroll
    for (int j = 0; j < 8; ++j) idx[j] = csr_src[min(g + j, end - 1)];
    uint32_t kw[8], vw[8];
#pragma unroll
    for (int j = 0; j < 8; ++j) {
      uint32_t off = ((uint32_t)idx[j] << 6) | (uint32_t)lane;
      kw[j] = K[off];
      vw[j] = V[off];
    }
    float sc[8];
#pragma unroll
    for (int j = 0; j < 8; ++j) {
      float p = qx * __uint_as_float(kw[j] << 16) + qy * __uint_as_float(kw[j] & 0xffff0000u);
      p = red8(p);
      sc[j] = (g + j < end) ? p : -INFINITY;
    }
    float mn = fmaxf(fmaxf(fmaxf(sc[0], sc[1]), fmaxf(sc[2], sc[3])),
                     fmaxf(fmaxf(sc[4], sc[5]), fmaxf(sc[6], fmaxf(sc[7], m2))));
    float scale = EXP2(m2 - mn);
    float wv[8];
#pragma unroll
    for (int j = 0; j < 8; ++j) wv[j] = EXP2(sc[j] - mn);
    float ws = (wv[0] + wv[1]) + (wv[2] + wv[3]) + ((wv[4] + wv[5]) + (wv[6] + wv[7]));
    float axn = 0.f, ayn = 0.f;
#pragma unroll
    for (int j = 0; j < 8; ++j) {
      axn += wv[j] * __uint_as_float(vw[j] << 16);
      ayn += wv[j] * __uint_as_float(vw[j] & 0xffff0000u);
    }
    sum = sum * scale + ws;
    ax = ax * scale + axn;
    ay = ay * scale + ayn;
    m2 = mn;
  }
  float inv = (sum > 0.f) ? 1.f / sum : 0.f;  // zero-degree nodes -> 0
  ((float2*)out)[(size_t)node * 64 + lane] = make_float2(ax * inv, ay * inv);
}

// ---------------- launch ----------------

extern "C" void kernel_launch(void* const* d_in, const int* in_sizes, int n_in,
                              void* d_out, int out_size, void* d_ws, size_t ws_size,
                              hipStream_t stream) {
  const float* h  = (const float*)d_in[0];
  const int* src  = (const int*)d_in[1];
  const int* dst  = (const int*)d_in[2];
  const float* WQ = (const float*)d_in[3];
  const float* bQ = (const float*)d_in[4];
  const float* WK = (const float*)d_in[5];
  const float* bK = (const float*)d_in[6];
  const float* WV = (const float*)d_in[7];
  const float* bV = (const float*)d_in[8];
  float* out = (float*)d_out;

  const int n = in_sizes[0] / HID;
  const int E = in_sizes[1];
  const int nb = (n + 255) / 256;

  ushort* Q = (ushort*)d_ws;
  ushort* K = Q + (size_t)n * HID;
  ushort* V = K + (size_t)n * HID;
  short* Wb = (short*)(V + (size_t)n * HID);        // 384*128
  int* counts  = (int*)(Wb + 384 * HID);
  int* offsets = counts + n;        // n+1 entries
  int* cursors = offsets + n + 1;
  int* csr_src = cursors + n;       // E entries
  int* bsum    = csr_src + E;       // nb entries

  hipMemsetAsync(counts, 0, (size_t)n * sizeof(int), stream);
  count_conv_kernel<<<(E + 255) / 256, 256, 0, stream>>>(dst, counts, E, WQ, WK, WV, Wb);
  scan1_kernel<<<nb, 256, 0, stream>>>(counts, offsets, bsum, n);
  scan2_kernel<<<1, 256, 0, stream>>>(bsum, offsets, nb, n);
  scan3_kernel<<<nb, 256, 0, stream>>>(offsets, cursors, bsum, n);
  scatter_kernel<<<(E + 255) / 256, 256, 0, stream>>>(src, dst, cursors, csr_src, E);
  qkv_mfma<<<(n + 63) / 64, 256, 0, stream>>>(h, Wb, bQ, bK, bV, Q, K, V, n);
  agg_kernel<<<(n + 3) / 4, 256, 0, stream>>>((const uint32_t*)Q, (const uint32_t*)K,
                                              (const uint32_t*)V, offsets, csr_src, out, n);
}